// Round 12
// baseline (1068.281 us; speedup 1.0000x reference)
//
#include <hip/hip_runtime.h>

// Feature dims fixed by the problem
constexpr int FIN = 64;   // input features
constexpr int FH  = 64;   // hidden
constexpr int FO  = 16;   // output

// edge_index arrives as int32 (harness integer convention), flat [2][E]:
// src = ei[e], dst = ei[e + E].

// Bucket sort parameters: bucket = dst >> 7 (128 nodes per bucket).
constexpr int BSH   = 7;
constexpr int BW    = 1 << BSH;   // 128 nodes / bucket
constexpr int NBUCK = 1024;       // covers N up to 131072
constexpr int EPB   = 16384;      // edges per chunk -> ~16-edge runs = full lines

// bf16 helpers (manual RNE; exact expand)
__device__ inline unsigned short f2bf(float f) {
    unsigned u = __float_as_uint(f);
    return (unsigned short)((u + 0x7FFFu + ((u >> 16) & 1u)) >> 16);
}
__device__ inline float bf2f(unsigned short h) {
    return __uint_as_float((unsigned)h << 16);
}
__device__ inline float4 bf4_to_f4(ushort4 u) {
    float4 f;
    f.x = bf2f(u.x); f.y = bf2f(u.y); f.z = bf2f(u.z); f.w = bf2f(u.w);
    return f;
}

// ---------------------------------------------------------------------------
// Kernel: per-chunk bucket histogram + bucket totals + node in-degree.
// All global atomics are fire-and-forget (no result dependency).
// ---------------------------------------------------------------------------
__launch_bounds__(256)
__global__ void hist_kernel(const int* __restrict__ ei, int E,
                            int* __restrict__ ccnt, int* __restrict__ bcnt,
                            int* __restrict__ degi) {
    __shared__ int lh[NBUCK];
    int t = threadIdx.x;
    for (int i = t; i < NBUCK; i += 256) lh[i] = 0;
    __syncthreads();
    int base = blockIdx.x * EPB;
    int lim  = min(E, base + EPB);
    for (int e = base + t; e < lim; e += 256) {
        int d = ei[E + e];
        atomicAdd(&lh[d >> BSH], 1);
        atomicAdd(&degi[d], 1);          // fire-and-forget
    }
    __syncthreads();
    int* crow = ccnt + (size_t)blockIdx.x * NBUCK;
    for (int b = t; b < NBUCK; b += 256) {
        int c = lh[b];
        crow[b] = c;
        if (c > 0) atomicAdd(&bcnt[b], c);
    }
}

// ---------------------------------------------------------------------------
// Kernel: dinv = rsqrt(deg + 1)
// ---------------------------------------------------------------------------
__global__ void dinv_kernel(const int* __restrict__ degi, float* __restrict__ dinv, int N) {
    int i = blockIdx.x * blockDim.x + threadIdx.x;
    if (i < N) dinv[i] = rsqrtf((float)(degi[i] + 1));
}

// ---------------------------------------------------------------------------
// Kernel: exclusive scan of bucket counts -> bbase[NBUCK+1].
// ---------------------------------------------------------------------------
__launch_bounds__(1024)
__global__ void bucket_scan_kernel(const int* __restrict__ bcnt, int* __restrict__ bbase,
                                   int E) {
    __shared__ int s[NBUCK];
    int t = threadIdx.x;
    int v = bcnt[t];
    s[t] = v;
    __syncthreads();
    for (int d = 1; d < NBUCK; d <<= 1) {
        int u = (t >= d) ? s[t - d] : 0;
        __syncthreads();
        s[t] += u;
        __syncthreads();
    }
    bbase[t] = s[t] - v;
    if (t == NBUCK - 1) bbase[NBUCK] = s[t];   // == E
}

// ---------------------------------------------------------------------------
// Kernel: per-bucket scan across chunks, in place: ccnt[c][b] becomes the
// absolute base of chunk c's run in bucket b. One thread per bucket.
// ---------------------------------------------------------------------------
__launch_bounds__(256)
__global__ void chunk_scan_kernel(int* __restrict__ ccnt, const int* __restrict__ bbase,
                                  int nchunk) {
    int b = blockIdx.x * 256 + threadIdx.x;
    if (b >= NBUCK) return;
    int base = bbase[b];
    int c = 0;
    for (; c + 8 <= nchunk; c += 8) {
        int* p0 = &ccnt[(size_t)(c + 0) * NBUCK + b];
        int* p1 = &ccnt[(size_t)(c + 1) * NBUCK + b];
        int* p2 = &ccnt[(size_t)(c + 2) * NBUCK + b];
        int* p3 = &ccnt[(size_t)(c + 3) * NBUCK + b];
        int* p4 = &ccnt[(size_t)(c + 4) * NBUCK + b];
        int* p5 = &ccnt[(size_t)(c + 5) * NBUCK + b];
        int* p6 = &ccnt[(size_t)(c + 6) * NBUCK + b];
        int* p7 = &ccnt[(size_t)(c + 7) * NBUCK + b];
        int v0 = *p0, v1 = *p1, v2 = *p2, v3 = *p3;
        int v4 = *p4, v5 = *p5, v6 = *p6, v7 = *p7;
        *p0 = base; base += v0;
        *p1 = base; base += v1;
        *p2 = base; base += v2;
        *p3 = base; base += v3;
        *p4 = base; base += v4;
        *p5 = base; base += v5;
        *p6 = base; base += v6;
        *p7 = base; base += v7;
    }
    for (; c < nchunk; ++c) {
        int* p = &ccnt[(size_t)c * NBUCK + b];
        int v = *p;
        *p = base; base += v;
    }
}

// ---------------------------------------------------------------------------
// Binning body: LDS cursors from precomputed chunk bases; single pass of
// LDS-cursor atomics + packed stores (src | dlocal<<17). Runs ~64 B.
// ---------------------------------------------------------------------------
__device__ inline void binning_body(const int* __restrict__ ei, int E, int chunk,
                                    const int* __restrict__ cbase,
                                    unsigned* __restrict__ ebuf, int* lh) {
    int t = threadIdx.x;
    const int* crow = cbase + (size_t)chunk * NBUCK;
    for (int i = t; i < NBUCK; i += 256) lh[i] = crow[i];
    __syncthreads();
    int base = chunk * EPB;
    int lim  = min(E, base + EPB);
    for (int e = base + t; e < lim; e += 256) {
        int d = ei[E + e];
        int srcv = ei[e];
        int pos = atomicAdd(&lh[d >> BSH], 1);
        ebuf[pos] = (unsigned)srcv | ((unsigned)(d & (BW - 1)) << 17);
    }
}

__launch_bounds__(256)
__global__ void binning_kernel(const int* __restrict__ ei, int E,
                               const int* __restrict__ cbase, unsigned* __restrict__ ebuf) {
    __shared__ int lh[NBUCK];
    binning_body(ei, E, blockIdx.x, cbase, ebuf, lh);
}

// ---------------------------------------------------------------------------
// Fused kernel: blocks [0, NBIN) do binning; blocks [NBIN, NBIN+G1T) do
// hsb = bf16((x @ W1) * dinv[row]) : 64-row tile, 4x4 per thread, W1 in LDS.
// ---------------------------------------------------------------------------
__launch_bounds__(256, 4)
__global__ void gemm1_binning_kernel(const float* __restrict__ x, const float* __restrict__ W1,
                                     const float* __restrict__ dinv,
                                     unsigned short* __restrict__ hsb,
                                     const int* __restrict__ ei, int E,
                                     const int* __restrict__ cbase, unsigned* __restrict__ ebuf,
                                     int N, int NBIN) {
    __shared__ float smem[FIN * FH];    // 16 KB: Ws for gemm, lh (4 KB) for binning
    int tid = threadIdx.x;
    if ((int)blockIdx.x < NBIN) {
        binning_body(ei, E, (int)blockIdx.x, cbase, ebuf, (int*)smem);
        return;
    }
    float* Ws = smem;                  // [64][64] row-major (k, col)
    {
        const float4* W14 = (const float4*)W1;
        float4* Ws4 = (float4*)smem;
        for (int i = tid; i < 1024; i += 256) Ws4[i] = W14[i];
    }
    __syncthreads();
    int cg = tid & 15;                 // col group: cols cg*4..+3
    int rg = tid >> 4;                 // row group: rows rg*4..+3
    int rowBase = ((int)blockIdx.x - NBIN) * 64;
    int r0 = rowBase + rg * 4;
    const float4* x4 = (const float4*)x;
    size_t ra = (size_t)min(r0 + 0, N - 1) * 16;
    size_t rb = (size_t)min(r0 + 1, N - 1) * 16;
    size_t rc = (size_t)min(r0 + 2, N - 1) * 16;
    size_t rd = (size_t)min(r0 + 3, N - 1) * 16;
    float4 acc0 = {0,0,0,0}, acc1 = {0,0,0,0}, acc2 = {0,0,0,0}, acc3 = {0,0,0,0};
    #pragma unroll 2
    for (int kc = 0; kc < 16; ++kc) {
        float4 xa0 = x4[ra + kc];
        float4 xa1 = x4[rb + kc];
        float4 xa2 = x4[rc + kc];
        float4 xa3 = x4[rd + kc];
        const float* xa0f = (const float*)&xa0;
        const float* xa1f = (const float*)&xa1;
        const float* xa2f = (const float*)&xa2;
        const float* xa3f = (const float*)&xa3;
        #pragma unroll
        for (int j = 0; j < 4; ++j) {
            float4 wv = *(const float4*)&Ws[(kc * 4 + j) * FH + cg * 4];
            float v0 = xa0f[j], v1 = xa1f[j], v2 = xa2f[j], v3 = xa3f[j];
            acc0.x = fmaf(v0, wv.x, acc0.x); acc0.y = fmaf(v0, wv.y, acc0.y);
            acc0.z = fmaf(v0, wv.z, acc0.z); acc0.w = fmaf(v0, wv.w, acc0.w);
            acc1.x = fmaf(v1, wv.x, acc1.x); acc1.y = fmaf(v1, wv.y, acc1.y);
            acc1.z = fmaf(v1, wv.z, acc1.z); acc1.w = fmaf(v1, wv.w, acc1.w);
            acc2.x = fmaf(v2, wv.x, acc2.x); acc2.y = fmaf(v2, wv.y, acc2.y);
            acc2.z = fmaf(v2, wv.z, acc2.z); acc2.w = fmaf(v2, wv.w, acc2.w);
            acc3.x = fmaf(v3, wv.x, acc3.x); acc3.y = fmaf(v3, wv.y, acc3.y);
            acc3.z = fmaf(v3, wv.z, acc3.z); acc3.w = fmaf(v3, wv.w, acc3.w);
        }
    }
    float d0 = dinv[min(r0 + 0, N - 1)];
    float d1 = dinv[min(r0 + 1, N - 1)];
    float d2 = dinv[min(r0 + 2, N - 1)];
    float d3 = dinv[min(r0 + 3, N - 1)];
    ushort4* hsb4 = (ushort4*)hsb;
    if (r0 + 0 < N) hsb4[(size_t)(r0 + 0) * 16 + cg] =
        make_ushort4(f2bf(acc0.x * d0), f2bf(acc0.y * d0), f2bf(acc0.z * d0), f2bf(acc0.w * d0));
    if (r0 + 1 < N) hsb4[(size_t)(r0 + 1) * 16 + cg] =
        make_ushort4(f2bf(acc1.x * d1), f2bf(acc1.y * d1), f2bf(acc1.z * d1), f2bf(acc1.w * d1));
    if (r0 + 2 < N) hsb4[(size_t)(r0 + 2) * 16 + cg] =
        make_ushort4(f2bf(acc2.x * d2), f2bf(acc2.y * d2), f2bf(acc2.z * d2), f2bf(acc2.w * d2));
    if (r0 + 3 < N) hsb4[(size_t)(r0 + 3) * 16 + cg] =
        make_ushort4(f2bf(acc3.x * d3), f2bf(acc3.y * d3), f2bf(acc3.z * d3), f2bf(acc3.w * d3));
}

// ---------------------------------------------------------------------------
// Kernel: layer-1 aggregation via bucket-private LDS accumulators, fused with
// finalize1 + GEMM2. One block per bucket: accf[128][65] init with self row,
// stream the bucket's ebuf run, gather hsb[src] (pre-scaled), ds_add_f32 into
// accf; epilogue applies dinv/bias/relu and GEMM2 -> hs2b (pre-scaled bf16).
// ---------------------------------------------------------------------------
__launch_bounds__(256)
__global__ void agg1_bucket_gemm2_kernel(const unsigned short* __restrict__ hsb,
                                         const unsigned* __restrict__ ebuf,
                                         const int* __restrict__ bbase,
                                         const float* __restrict__ dinv,
                                         const float* __restrict__ b1,
                                         const float* __restrict__ W2,
                                         unsigned short* __restrict__ hs2b, int N) {
    __shared__ float accf[BW][FH + 1];   // 33.3 KB, +1 pad spreads banks
    __shared__ float W2s[FH * FO];       // 4 KB
    __shared__ float b1s[FH];
    __shared__ float dval[BW];
    const ushort4* hs4 = (const ushort4*)hsb;
    int t = threadIdx.x;
    int b = blockIdx.x;
    int nodeBase = b << BSH;
    for (int i = t; i < FH * FO; i += 256) W2s[i] = W2[i];
    if (t < FH) b1s[t] = b1[t];
    if (t < BW) {
        int node = nodeBase + t;
        dval[t] = (node < N) ? dinv[node] : 0.f;
    }
    // init accf with self contribution (hsb is pre-scaled by dinv)
    for (int k = t; k < BW * 16; k += 256) {
        int ln = k >> 4, c = k & 15;
        int node = nodeBase + ln;
        float4 v = (node < N) ? bf4_to_f4(hs4[(size_t)node * 16 + c])
                              : make_float4(0.f, 0.f, 0.f, 0.f);
        accf[ln][c * 4 + 0] = v.x;
        accf[ln][c * 4 + 1] = v.y;
        accf[ln][c * 4 + 2] = v.z;
        accf[ln][c * 4 + 3] = v.w;
    }
    __syncthreads();
    int beg = bbase[b], end = bbase[b + 1];
    int l = t & 15;
    for (int i = beg + (t >> 4); i < end; i += 16) {
        unsigned w = ebuf[i];
        int src = (int)(w & 0x1FFFF);
        int dl  = (int)(w >> 17);
        float4 a = bf4_to_f4(hs4[(size_t)src * 16 + l]);
        atomicAdd(&accf[dl][l * 4 + 0], a.x);
        atomicAdd(&accf[dl][l * 4 + 1], a.y);
        atomicAdd(&accf[dl][l * 4 + 2], a.z);
        atomicAdd(&accf[dl][l * 4 + 3], a.w);
    }
    __syncthreads();
    // epilogue: h1 = relu(dinv*acc + b1); hs2 = (h1 @ W2) * dinv
    int r2 = t >> 4, o = t & 15;
    for (int ng = 0; ng < BW / 16; ++ng) {
        int ln = ng * 16 + r2;
        int node = nodeBase + ln;
        if (node < N) {
            float di = dval[ln];
            float acc = 0.f;
            #pragma unroll
            for (int j = 0; j < FH; ++j) {
                float hv = fmaxf(fmaf(di, accf[ln][j], b1s[j]), 0.f);
                acc = fmaf(hv, W2s[j * FO + o], acc);
            }
            hs2b[(size_t)node * FO + o] = f2bf(acc * di);
        }
    }
}

// ---------------------------------------------------------------------------
// Kernel: layer-2 aggregation via bucket-private LDS + bias + log_softmax.
// ---------------------------------------------------------------------------
__launch_bounds__(256)
__global__ void agg2_bucket_softmax_kernel(const unsigned short* __restrict__ hs2b,
                                           const unsigned* __restrict__ ebuf,
                                           const int* __restrict__ bbase,
                                           const float* __restrict__ dinv,
                                           const float* __restrict__ b2,
                                           float* __restrict__ out, int N) {
    __shared__ float acc2[BW][FO + 1];   // 8.7 KB, +1 pad
    __shared__ float dval[BW];
    __shared__ float b2s[FO];
    int t = threadIdx.x;
    int b = blockIdx.x;
    int nodeBase = b << BSH;
    if (t < FO) b2s[t] = b2[t];
    if (t < BW) {
        int node = nodeBase + t;
        dval[t] = (node < N) ? dinv[node] : 0.f;
    }
    for (int k = t; k < BW * FO; k += 256) {
        int ln = k >> 4, o = k & 15;
        int node = nodeBase + ln;
        acc2[ln][o] = (node < N) ? bf2f(hs2b[(size_t)node * FO + o]) : 0.f;
    }
    __syncthreads();
    int beg = bbase[b], end = bbase[b + 1];
    int o = t & 15;
    for (int i = beg + (t >> 4); i < end; i += 16) {
        unsigned w = ebuf[i];
        int src = (int)(w & 0x1FFFF);
        int dl  = (int)(w >> 17);
        atomicAdd(&acc2[dl][o], bf2f(hs2b[(size_t)src * FO + o]));
    }
    __syncthreads();
    int r2 = t >> 4;
    for (int ng = 0; ng < BW / 16; ++ng) {
        int ln = ng * 16 + r2;
        int node = nodeBase + ln;
        float v = (node < N) ? fmaf(dval[ln], acc2[ln][o], b2s[o]) : 0.f;
        float m = v;
        #pragma unroll
        for (int s = 8; s >= 1; s >>= 1) m = fmaxf(m, __shfl_xor(m, s, 64));
        float ex = __expf(v - m);
        float sum = ex;
        #pragma unroll
        for (int s = 8; s >= 1; s >>= 1) sum += __shfl_xor(sum, s, 64);
        if (node < N) out[(size_t)node * FO + o] = v - m - __logf(sum);
    }
}

// ---------------------------------------------------------------------------
extern "C" void kernel_launch(void* const* d_in, const int* in_sizes, int n_in,
                              void* d_out, int out_size, void* d_ws, size_t ws_size,
                              hipStream_t stream) {
    const float* x  = (const float*)d_in[0];
    const int*   ei = (const int*)d_in[1];     // int32
    const float* W1 = (const float*)d_in[2];
    const float* b1 = (const float*)d_in[3];
    const float* W2 = (const float*)d_in[4];
    const float* b2 = (const float*)d_in[5];
    float* out = (float*)d_out;

    const int N = in_sizes[0] / FIN;
    const int E = in_sizes[1] / 2;
    const int NCB  = (E + EPB - 1) / EPB;            // chunks (hist + binning)
    const int NB4  = (N + BW - 1) / BW;              // buckets actually used
    const int G1T  = (N + 63) / 64;                  // gemm 64-row tiles

    char* ws = (char*)d_ws;
    size_t off = 0;
    auto alloc = [&](size_t bytes) -> void* {
        off = (off + 255) & ~(size_t)255;
        void* p = ws + off;
        off += bytes;
        return p;
    };
    // zero-region first (degi + bcnt contiguous; one memset)
    int*            degi  = (int*)alloc((size_t)N * 4);                 //  0.4 MB
    int*            bcnt  = (int*)alloc(NBUCK * 4);
    size_t zero_end = off;
    float*          dinv  = (float*)alloc((size_t)N * 4);               //  0.4 MB
    unsigned short* hsb   = (unsigned short*)alloc((size_t)N * FH * 2); // 12.8 MB
    unsigned short* hs2b  = (unsigned short*)alloc((size_t)N * FO * 2); //  3.2 MB
    int*            bbase = (int*)alloc((NBUCK + 1) * 4);
    int*            ccnt  = (int*)alloc((size_t)NCB * NBUCK * 4);       //  0.4 MB
    // ebuf (E ints = 6.4 MB): in ws if it fits, else alias the x input buffer
    // (dead after the gemm phase; harness restores d_in before every launch;
    // ws_size constant -> capture-stable branch).
    unsigned* ebuf;
    bool ws_fits = (ws_size >= off + 256 + (size_t)E * 4);
    if (ws_fits) {
        ebuf = (unsigned*)alloc((size_t)E * 4);
    } else {
        ebuf = (unsigned*)x;
    }

    hipMemsetAsync(degi, 0, zero_end, stream);   // degi starts at ws offset 0

    hist_kernel<<<NCB, 256, 0, stream>>>(ei, E, ccnt, bcnt, degi);
    dinv_kernel<<<(N + 255) / 256, 256, 0, stream>>>(degi, dinv, N);
    bucket_scan_kernel<<<1, NBUCK, 0, stream>>>(bcnt, bbase, E);
    chunk_scan_kernel<<<NBUCK / 256, 256, 0, stream>>>(ccnt, bbase, NCB);
    if (ws_fits) {
        // Overlap: binning blocks first (latency-bound), gemm blocks backfill.
        gemm1_binning_kernel<<<NCB + G1T, 256, 0, stream>>>(x, W1, dinv, hsb, ei, E,
                                                            ccnt, ebuf, N, NCB);
    } else {
        // ebuf aliases x: gemm must fully precede binning.
        gemm1_binning_kernel<<<G1T, 256, 0, stream>>>(x, W1, dinv, hsb, ei, E,
                                                      ccnt, ebuf, N, 0);
        binning_kernel<<<NCB, 256, 0, stream>>>(ei, E, ccnt, ebuf);
    }
    agg1_bucket_gemm2_kernel<<<NB4, 256, 0, stream>>>(hsb, ebuf, bbase, dinv, b1, W2, hs2b, N);
    agg2_bucket_softmax_kernel<<<NB4, 256, 0, stream>>>(hs2b, ebuf, bbase, dinv, b2, out, N);
}

// Round 13
// 224.549 us; speedup vs baseline: 4.7575x; 4.7575x over previous
//
#include <hip/hip_runtime.h>

// Feature dims fixed by the problem
constexpr int FIN = 64;   // input features
constexpr int FH  = 64;   // hidden
constexpr int FO  = 16;   // output

// edge_index arrives as int32 (harness integer convention), flat [2][E]:
// src = ei[e], dst = ei[e + E].

// Bucket sort parameters: bucket = dst >> 7 (128 nodes per bucket).
constexpr int BSH      = 7;
constexpr int BW       = 1 << BSH;  // 128 nodes / bucket
constexpr int NBUCK    = 1024;      // covers N up to 131072
constexpr int EPB_HIST = 16384;     // edges per hist block
constexpr int EPB_BIN  = 16384;     // edges per binning block: ~16-edge runs
                                    // = 64 B full-line ebuf stores (r11 found
                                    // 4096 -> 16 B runs -> 4x write amp)

// bf16 helpers (manual RNE; exact expand)
__device__ inline unsigned short f2bf(float f) {
    unsigned u = __float_as_uint(f);
    return (unsigned short)((u + 0x7FFFu + ((u >> 16) & 1u)) >> 16);
}
__device__ inline float bf2f(unsigned short h) {
    return __uint_as_float((unsigned)h << 16);
}
__device__ inline float4 bf4_to_f4(ushort4 u) {
    float4 f;
    f.x = bf2f(u.x); f.y = bf2f(u.y); f.z = bf2f(u.z); f.w = bf2f(u.w);
    return f;
}

// ---------------------------------------------------------------------------
// Kernel: dst-bucket histogram (fire-and-forget global atomics).
// ---------------------------------------------------------------------------
__launch_bounds__(256)
__global__ void hist_kernel(const int* __restrict__ ei, int E, int* __restrict__ bcnt) {
    __shared__ int lh[NBUCK];
    int t = threadIdx.x;
    for (int i = t; i < NBUCK; i += 256) lh[i] = 0;
    __syncthreads();
    int base = blockIdx.x * EPB_HIST;
    int lim  = min(E, base + EPB_HIST);
    for (int e = base + t; e < lim; e += 256)
        atomicAdd(&lh[ei[E + e] >> BSH], 1);
    __syncthreads();
    for (int b = t; b < NBUCK; b += 256) {
        int c = lh[b];
        if (c > 0) atomicAdd(&bcnt[b], c);
    }
}

// ---------------------------------------------------------------------------
// Kernel: exclusive scan of bucket counts -> bbase[NBUCK+1], init gcur.
// Single block of 1024 threads. Also writes offs[N] = E.
// ---------------------------------------------------------------------------
__launch_bounds__(1024)
__global__ void bucket_scan_kernel(const int* __restrict__ bcnt, int* __restrict__ bbase,
                                   int* __restrict__ gcur, int* __restrict__ offs,
                                   int N, int E) {
    __shared__ int s[NBUCK];
    int t = threadIdx.x;
    int v = bcnt[t];
    s[t] = v;
    __syncthreads();
    for (int d = 1; d < NBUCK; d <<= 1) {
        int u = (t >= d) ? s[t - d] : 0;
        __syncthreads();
        s[t] += u;
        __syncthreads();
    }
    int ex = s[t] - v;
    bbase[t] = ex;
    gcur[t]  = ex;
    if (t == NBUCK - 1) {
        bbase[NBUCK] = s[t];   // == E
        offs[N] = E;
    }
}

// ---------------------------------------------------------------------------
// Binning device body: reserve contiguous per-bucket runs, write each edge
// once as packed word src | (dst & 127) << 17 (N < 2^17).
// ---------------------------------------------------------------------------
__device__ inline void binning_body(const int* __restrict__ ei, int E, int chunk,
                                    int* __restrict__ gcur, unsigned* __restrict__ ebuf,
                                    int* lh) {
    int t = threadIdx.x;
    for (int i = t; i < NBUCK; i += 256) lh[i] = 0;
    __syncthreads();
    int base = chunk * EPB_BIN;
    int lim  = min(E, base + EPB_BIN);
    for (int e = base + t; e < lim; e += 256)
        atomicAdd(&lh[ei[E + e] >> BSH], 1);
    __syncthreads();
    for (int b = t; b < NBUCK; b += 256) {
        int c = lh[b];
        lh[b] = (c > 0) ? atomicAdd(&gcur[b], c) : 0;   // run base -> running cursor
    }
    __syncthreads();
    for (int e = base + t; e < lim; e += 256) {
        int d = ei[E + e];
        int srcv = ei[e];
        int pos = atomicAdd(&lh[d >> BSH], 1);
        ebuf[pos] = (unsigned)srcv | ((unsigned)(d & (BW - 1)) << 17);
    }
}

__launch_bounds__(256)
__global__ void binning_kernel(const int* __restrict__ ei, int E,
                               int* __restrict__ gcur, unsigned* __restrict__ ebuf) {
    __shared__ int lh[NBUCK];
    binning_body(ei, E, blockIdx.x, gcur, ebuf, lh);
}

// ---------------------------------------------------------------------------
// Fused kernel: blocks [0, NBIN) do binning (latency-bound, start first);
// blocks [NBIN, NBIN+G1T) do hs_bf16 = bf16(x @ W1): 64-row tile, 4x4 per
// thread. W1 in LDS (16 KB, conflict-free); x read directly from global
// (16-lane broadcast per row). __launch_bounds__(256,4) caps VGPRs (round-9
// lesson: full unroll -> 240 VGPRs -> 9.6% occupancy).
// ---------------------------------------------------------------------------
__launch_bounds__(256, 4)
__global__ void gemm1_binning_kernel(const float* __restrict__ x, const float* __restrict__ W1,
                                     unsigned short* __restrict__ hsb,
                                     const int* __restrict__ ei, int E,
                                     int* __restrict__ gcur, unsigned* __restrict__ ebuf,
                                     int N, int NBIN) {
    __shared__ float smem[FIN * FH];    // 16 KB: Ws for gemm, lh (4 KB) for binning
    int tid = threadIdx.x;
    if ((int)blockIdx.x < NBIN) {
        binning_body(ei, E, (int)blockIdx.x, gcur, ebuf, (int*)smem);
        return;
    }
    // ---- GEMM phase ----
    float* Ws = smem;                  // [64][64] row-major (k, col)
    {
        const float4* W14 = (const float4*)W1;
        float4* Ws4 = (float4*)smem;
        for (int i = tid; i < 1024; i += 256) Ws4[i] = W14[i];
    }
    __syncthreads();
    int cg = tid & 15;                 // col group: cols cg*4..+3
    int rg = tid >> 4;                 // row group: rows rg*4..+3
    int rowBase = ((int)blockIdx.x - NBIN) * 64;
    int r0 = rowBase + rg * 4;
    const float4* x4 = (const float4*)x;
    size_t ra = (size_t)min(r0 + 0, N - 1) * 16;
    size_t rb = (size_t)min(r0 + 1, N - 1) * 16;
    size_t rc = (size_t)min(r0 + 2, N - 1) * 16;
    size_t rd = (size_t)min(r0 + 3, N - 1) * 16;
    float4 acc0 = {0,0,0,0}, acc1 = {0,0,0,0}, acc2 = {0,0,0,0}, acc3 = {0,0,0,0};
    #pragma unroll 2
    for (int kc = 0; kc < 16; ++kc) {
        float4 xa0 = x4[ra + kc];
        float4 xa1 = x4[rb + kc];
        float4 xa2 = x4[rc + kc];
        float4 xa3 = x4[rd + kc];
        const float* xa0f = (const float*)&xa0;
        const float* xa1f = (const float*)&xa1;
        const float* xa2f = (const float*)&xa2;
        const float* xa3f = (const float*)&xa3;
        #pragma unroll
        for (int j = 0; j < 4; ++j) {
            float4 wv = *(const float4*)&Ws[(kc * 4 + j) * FH + cg * 4];
            float v0 = xa0f[j], v1 = xa1f[j], v2 = xa2f[j], v3 = xa3f[j];
            acc0.x = fmaf(v0, wv.x, acc0.x); acc0.y = fmaf(v0, wv.y, acc0.y);
            acc0.z = fmaf(v0, wv.z, acc0.z); acc0.w = fmaf(v0, wv.w, acc0.w);
            acc1.x = fmaf(v1, wv.x, acc1.x); acc1.y = fmaf(v1, wv.y, acc1.y);
            acc1.z = fmaf(v1, wv.z, acc1.z); acc1.w = fmaf(v1, wv.w, acc1.w);
            acc2.x = fmaf(v2, wv.x, acc2.x); acc2.y = fmaf(v2, wv.y, acc2.y);
            acc2.z = fmaf(v2, wv.z, acc2.z); acc2.w = fmaf(v2, wv.w, acc2.w);
            acc3.x = fmaf(v3, wv.x, acc3.x); acc3.y = fmaf(v3, wv.y, acc3.y);
            acc3.z = fmaf(v3, wv.z, acc3.z); acc3.w = fmaf(v3, wv.w, acc3.w);
        }
    }
    ushort4* hsb4 = (ushort4*)hsb;
    if (r0 + 0 < N) hsb4[(size_t)(r0 + 0) * 16 + cg] =
        make_ushort4(f2bf(acc0.x), f2bf(acc0.y), f2bf(acc0.z), f2bf(acc0.w));
    if (r0 + 1 < N) hsb4[(size_t)(r0 + 1) * 16 + cg] =
        make_ushort4(f2bf(acc1.x), f2bf(acc1.y), f2bf(acc1.z), f2bf(acc1.w));
    if (r0 + 2 < N) hsb4[(size_t)(r0 + 2) * 16 + cg] =
        make_ushort4(f2bf(acc2.x), f2bf(acc2.y), f2bf(acc2.z), f2bf(acc2.w));
    if (r0 + 3 < N) hsb4[(size_t)(r0 + 3) * 16 + cg] =
        make_ushort4(f2bf(acc3.x), f2bf(acc3.y), f2bf(acc3.z), f2bf(acc3.w));
}

// ---------------------------------------------------------------------------
// Kernel: per-bucket CSR build + dinv + offs. One block per bucket; all csr
// stores land in the block's own contiguous region (single-owner lines).
// ---------------------------------------------------------------------------
__launch_bounds__(256)
__global__ void bucket_csr_kernel(const unsigned* __restrict__ ebuf,
                                  const int* __restrict__ bbase,
                                  int* __restrict__ csr, int* __restrict__ offs,
                                  float* __restrict__ dinv, int N) {
    __shared__ int cnt[BW], sc[BW], cur[BW];
    int t = threadIdx.x;
    int b = blockIdx.x;
    if (t < BW) cnt[t] = 0;
    __syncthreads();
    int beg = bbase[b], end = bbase[b + 1];
    for (int i = beg + t; i < end; i += 256)
        atomicAdd(&cnt[ebuf[i] >> 17], 1);
    __syncthreads();
    if (t < BW) sc[t] = cnt[t];
    __syncthreads();
    for (int d = 1; d < BW; d <<= 1) {
        int u = (t < BW && t >= d) ? sc[t - d] : 0;
        __syncthreads();
        if (t < BW) sc[t] += u;
        __syncthreads();
    }
    int nodeBase = b << BSH;
    if (t < BW) {
        int node = nodeBase + t;
        int ex = beg + sc[t] - cnt[t];
        cur[t] = ex;
        if (node < N) {
            offs[node] = ex;
            dinv[node] = rsqrtf((float)(cnt[t] + 1));
        }
    }
    __syncthreads();
    for (int i = beg + t; i < end; i += 256) {
        unsigned w = ebuf[i];
        int pos = atomicAdd(&cur[w >> 17], 1);
        csr[pos] = (int)(w & 0x1FFFF);
    }
}

// ---------------------------------------------------------------------------
// Kernel: layer-1 PULL aggregation (bf16 gathers, 8 in flight, per-src dinv
// scale in-reg) fused with finalize1 + GEMM2; writes hs2 pre-scaled as bf16.
// 16 nodes/block; 16 lanes per node, lane owns one ushort4 chunk (4 feats).
// ---------------------------------------------------------------------------
__launch_bounds__(256)
__global__ void agg1_gemm2_kernel(const unsigned short* __restrict__ hsb,
                                  const int* __restrict__ csr,
                                  const int* __restrict__ offs, const float* __restrict__ dinv,
                                  const float* __restrict__ b1, const float* __restrict__ W2,
                                  unsigned short* __restrict__ hs2b, int N) {
    __shared__ float W2s[FH * FO];       // 4 KB
    __shared__ float h1s[16][68];        // 68-float row stride (16B-aligned, non-pow2)
    const ushort4* hs4 = (const ushort4*)hsb;   // 16 ushort4 per row
    int tid = threadIdx.x;
    for (int i = tid; i < FH * FO; i += 256) W2s[i] = W2[i];
    int g = tid >> 4, l = tid & 15;
    int n = blockIdx.x * 16 + g;
    if (n < N) {
        float di_n = dinv[n];
        float4 self = bf4_to_f4(hs4[(size_t)n * 16 + l]);
        float4 acc;
        acc.x = self.x * di_n; acc.y = self.y * di_n;
        acc.z = self.z * di_n; acc.w = self.w * di_n;
        int j = offs[n], end = offs[n + 1];
        for (; j + 7 < end; j += 8) {              // 8 gathers in flight
            int s0 = csr[j],     s1 = csr[j + 1], s2 = csr[j + 2], s3 = csr[j + 3];
            int s4 = csr[j + 4], s5 = csr[j + 5], s6 = csr[j + 6], s7 = csr[j + 7];
            float d0 = dinv[s0], d1 = dinv[s1], d2 = dinv[s2], d3 = dinv[s3];
            float d4 = dinv[s4], d5 = dinv[s5], d6 = dinv[s6], d7 = dinv[s7];
            float4 a0 = bf4_to_f4(hs4[(size_t)s0 * 16 + l]);
            float4 a1 = bf4_to_f4(hs4[(size_t)s1 * 16 + l]);
            float4 a2 = bf4_to_f4(hs4[(size_t)s2 * 16 + l]);
            float4 a3 = bf4_to_f4(hs4[(size_t)s3 * 16 + l]);
            float4 a4 = bf4_to_f4(hs4[(size_t)s4 * 16 + l]);
            float4 a5 = bf4_to_f4(hs4[(size_t)s5 * 16 + l]);
            float4 a6 = bf4_to_f4(hs4[(size_t)s6 * 16 + l]);
            float4 a7 = bf4_to_f4(hs4[(size_t)s7 * 16 + l]);
            acc.x += (fmaf(a0.x, d0, a1.x * d1) + fmaf(a2.x, d2, a3.x * d3))
                   + (fmaf(a4.x, d4, a5.x * d5) + fmaf(a6.x, d6, a7.x * d7));
            acc.y += (fmaf(a0.y, d0, a1.y * d1) + fmaf(a2.y, d2, a3.y * d3))
                   + (fmaf(a4.y, d4, a5.y * d5) + fmaf(a6.y, d6, a7.y * d7));
            acc.z += (fmaf(a0.z, d0, a1.z * d1) + fmaf(a2.z, d2, a3.z * d3))
                   + (fmaf(a4.z, d4, a5.z * d5) + fmaf(a6.z, d6, a7.z * d7));
            acc.w += (fmaf(a0.w, d0, a1.w * d1) + fmaf(a2.w, d2, a3.w * d3))
                   + (fmaf(a4.w, d4, a5.w * d5) + fmaf(a6.w, d6, a7.w * d7));
        }
        for (; j + 1 < end; j += 2) {
            int s0 = csr[j], s1 = csr[j + 1];
            float d0 = dinv[s0], d1 = dinv[s1];
            float4 a0 = bf4_to_f4(hs4[(size_t)s0 * 16 + l]);
            float4 a1 = bf4_to_f4(hs4[(size_t)s1 * 16 + l]);
            acc.x += fmaf(a0.x, d0, a1.x * d1);
            acc.y += fmaf(a0.y, d0, a1.y * d1);
            acc.z += fmaf(a0.z, d0, a1.z * d1);
            acc.w += fmaf(a0.w, d0, a1.w * d1);
        }
        if (j < end) {
            int s0 = csr[j];
            float d0 = dinv[s0];
            float4 a0 = bf4_to_f4(hs4[(size_t)s0 * 16 + l]);
            acc.x = fmaf(a0.x, d0, acc.x); acc.y = fmaf(a0.y, d0, acc.y);
            acc.z = fmaf(a0.z, d0, acc.z); acc.w = fmaf(a0.w, d0, acc.w);
        }
        float4 bb = ((const float4*)b1)[l];
        float4 h;
        h.x = fmaxf(fmaf(di_n, acc.x, bb.x), 0.f);
        h.y = fmaxf(fmaf(di_n, acc.y, bb.y), 0.f);
        h.z = fmaxf(fmaf(di_n, acc.z, bb.z), 0.f);
        h.w = fmaxf(fmaf(di_n, acc.w, bb.w), 0.f);
        *((float4*)&h1s[g][l * 4]) = h;
    }
    __syncthreads();
    int r = tid >> 4, o = tid & 15;     // 16 rows x 16 out-cols
    int n2 = blockIdx.x * 16 + r;
    if (n2 < N) {
        float acc = 0.f;
        #pragma unroll
        for (int jj = 0; jj < FH; ++jj)
            acc = fmaf(h1s[r][jj], W2s[jj * FO + o], acc);
        hs2b[(size_t)n2 * FO + o] = f2bf(acc * dinv[n2]);   // pre-scaled bf16
    }
}

// ---------------------------------------------------------------------------
// Kernel: layer-2 PULL aggregation (8 gathers in flight) + bias + log_softmax.
// hs2b table is 3.2 MB -> fits per-XCD L2; gathers are 2B/lane.
// ---------------------------------------------------------------------------
__launch_bounds__(256)
__global__ void agg2_softmax_kernel(const unsigned short* __restrict__ hs2b,
                                    const int* __restrict__ csr,
                                    const int* __restrict__ offs, const float* __restrict__ dinv,
                                    const float* __restrict__ b2, float* __restrict__ out, int N) {
    int tid = threadIdx.x;
    int g = tid >> 4, o = tid & 15;
    int n = blockIdx.x * 16 + g;
    float v = 0.f;
    if (n < N) {
        float acc = bf2f(hs2b[(size_t)n * 16 + o]);    // self loop (pre-scaled)
        int j = offs[n], end = offs[n + 1];
        for (; j + 7 < end; j += 8) {
            int s0 = csr[j],     s1 = csr[j + 1], s2 = csr[j + 2], s3 = csr[j + 3];
            int s4 = csr[j + 4], s5 = csr[j + 5], s6 = csr[j + 6], s7 = csr[j + 7];
            float t0 = bf2f(hs2b[(size_t)s0 * 16 + o]) + bf2f(hs2b[(size_t)s1 * 16 + o]);
            float t1 = bf2f(hs2b[(size_t)s2 * 16 + o]) + bf2f(hs2b[(size_t)s3 * 16 + o]);
            float t2 = bf2f(hs2b[(size_t)s4 * 16 + o]) + bf2f(hs2b[(size_t)s5 * 16 + o]);
            float t3 = bf2f(hs2b[(size_t)s6 * 16 + o]) + bf2f(hs2b[(size_t)s7 * 16 + o]);
            acc += (t0 + t1) + (t2 + t3);
        }
        for (; j < end; ++j) acc += bf2f(hs2b[(size_t)csr[j] * 16 + o]);
        v = fmaf(dinv[n], acc, b2[o]);
    }
    float m = v;
    #pragma unroll
    for (int s = 8; s >= 1; s >>= 1) m = fmaxf(m, __shfl_xor(m, s, 64));
    float ex = __expf(v - m);
    float sum = ex;
    #pragma unroll
    for (int s = 8; s >= 1; s >>= 1) sum += __shfl_xor(sum, s, 64);
    if (n < N) out[(size_t)n * FO + o] = v - m - __logf(sum);
}

// ---------------------------------------------------------------------------
extern "C" void kernel_launch(void* const* d_in, const int* in_sizes, int n_in,
                              void* d_out, int out_size, void* d_ws, size_t ws_size,
                              hipStream_t stream) {
    const float* x  = (const float*)d_in[0];
    const int*   ei = (const int*)d_in[1];     // int32
    const float* W1 = (const float*)d_in[2];
    const float* b1 = (const float*)d_in[3];
    const float* W2 = (const float*)d_in[4];
    const float* b2 = (const float*)d_in[5];
    float* out = (float*)d_out;

    const int N = in_sizes[0] / FIN;
    const int E = in_sizes[1] / 2;
    const int NCH  = (E + EPB_HIST - 1) / EPB_HIST;  // hist blocks
    const int NCB  = (E + EPB_BIN - 1) / EPB_BIN;    // binning blocks
    const int NB4  = (N + BW - 1) / BW;              // buckets actually used
    const int G1T  = (N + 63) / 64;                  // gemm 64-row tiles
    const int GA   = (N + 15) / 16;                  // agg blocks

    char* ws = (char*)d_ws;
    size_t off = 0;
    auto alloc = [&](size_t bytes) -> void* {
        off = (off + 255) & ~(size_t)255;
        void* p = ws + off;
        off += bytes;
        return p;
    };
    float*          dinv  = (float*)alloc((size_t)N * 4);               //  0.4 MB
    unsigned short* hsb   = (unsigned short*)alloc((size_t)N * FH * 2); // 12.8 MB
    unsigned short* hs2b  = (unsigned short*)alloc((size_t)N * FO * 2); //  3.2 MB
    int*            offs  = (int*)alloc((size_t)(N + 1) * 4);           //  0.4 MB
    int*            bcnt  = (int*)alloc(NBUCK * 4);
    int*            bbase = (int*)alloc((NBUCK + 1) * 4);
    int*            gcur  = (int*)alloc(NBUCK * 4);
    // ebuf + csr (2*E ints = 12.8 MB): in ws if it fits, else alias the x
    // input buffer (25.6 MB, dead after the gemm phase; harness restores d_in
    // before every launch; ws_size constant -> capture-stable branch).
    unsigned* ebuf;
    int*      csr;
    bool ws_fits = (ws_size >= off + 512 + (size_t)E * 8);
    if (ws_fits) {
        ebuf = (unsigned*)alloc((size_t)E * 4);
        csr  = (int*)     alloc((size_t)E * 4);
    } else {
        ebuf = (unsigned*)x;
        csr  = (int*)x + E;
    }

    hipMemsetAsync(bcnt, 0, NBUCK * 4, stream);

    hist_kernel<<<NCH, 256, 0, stream>>>(ei, E, bcnt);
    bucket_scan_kernel<<<1, NBUCK, 0, stream>>>(bcnt, bbase, gcur, offs, N, E);
    if (ws_fits) {
        // Overlap: binning blocks first (latency-bound), gemm blocks backfill.
        gemm1_binning_kernel<<<NCB + G1T, 256, 0, stream>>>(x, W1, hsb, ei, E,
                                                            gcur, ebuf, N, NCB);
    } else {
        // ebuf aliases x: gemm must fully precede binning.
        gemm1_binning_kernel<<<G1T, 256, 0, stream>>>(x, W1, hsb, ei, E,
                                                      gcur, ebuf, N, 0);
        binning_kernel<<<NCB, 256, 0, stream>>>(ei, E, gcur, ebuf);
    }
    bucket_csr_kernel<<<NB4, 256, 0, stream>>>(ebuf, bbase, csr, offs, dinv, N);
    agg1_gemm2_kernel<<<GA, 256, 0, stream>>>(hsb, csr, offs, dinv, b1, W2, hs2b, N);
    agg2_softmax_kernel<<<GA, 256, 0, stream>>>(hs2b, csr, offs, dinv, b2, out, N);
}

// Round 14
// 217.291 us; speedup vs baseline: 4.9164x; 1.0334x over previous
//
#include <hip/hip_runtime.h>

// Feature dims fixed by the problem
constexpr int FIN = 64;   // input features
constexpr int FH  = 64;   // hidden
constexpr int FO  = 16;   // output

// edge_index arrives as int32 (harness integer convention), flat [2][E]:
// src = ei[e], dst = ei[e + E].

// Bucket sort parameters: bucket = dst >> 7 (128 nodes per bucket).
constexpr int BSH      = 7;
constexpr int BW       = 1 << BSH;  // 128 nodes / bucket
constexpr int NBUCK    = 1024;      // covers N up to 131072
constexpr int EPB_HIST = 16384;     // edges per hist block
constexpr int EPB_BIN  = 4096;      // edges per binning block (r13 showed 16384
                                    // makes 98 long blocks the tail; 4096 best)

// bf16 helpers (manual RNE; exact expand)
__device__ inline unsigned short f2bf(float f) {
    unsigned u = __float_as_uint(f);
    return (unsigned short)((u + 0x7FFFu + ((u >> 16) & 1u)) >> 16);
}
__device__ inline float bf2f(unsigned short h) {
    return __uint_as_float((unsigned)h << 16);
}
__device__ inline float4 bf4_to_f4(ushort4 u) {
    float4 f;
    f.x = bf2f(u.x); f.y = bf2f(u.y); f.z = bf2f(u.z); f.w = bf2f(u.w);
    return f;
}

// ---------------------------------------------------------------------------
// Kernel: dst-bucket histogram (fire-and-forget global atomics).
// ---------------------------------------------------------------------------
__launch_bounds__(256)
__global__ void hist_kernel(const int* __restrict__ ei, int E, int* __restrict__ bcnt) {
    __shared__ int lh[NBUCK];
    int t = threadIdx.x;
    for (int i = t; i < NBUCK; i += 256) lh[i] = 0;
    __syncthreads();
    int base = blockIdx.x * EPB_HIST;
    int lim  = min(E, base + EPB_HIST);
    for (int e = base + t; e < lim; e += 256)
        atomicAdd(&lh[ei[E + e] >> BSH], 1);
    __syncthreads();
    for (int b = t; b < NBUCK; b += 256) {
        int c = lh[b];
        if (c > 0) atomicAdd(&bcnt[b], c);
    }
}

// ---------------------------------------------------------------------------
// Kernel: exclusive scan of bucket counts -> bbase[NBUCK+1], init gcur.
// Single block of 1024 threads. Also writes offs[N] = E.
// ---------------------------------------------------------------------------
__launch_bounds__(1024)
__global__ void bucket_scan_kernel(const int* __restrict__ bcnt, int* __restrict__ bbase,
                                   int* __restrict__ gcur, int* __restrict__ offs,
                                   int N, int E) {
    __shared__ int s[NBUCK];
    int t = threadIdx.x;
    int v = bcnt[t];
    s[t] = v;
    __syncthreads();
    for (int d = 1; d < NBUCK; d <<= 1) {
        int u = (t >= d) ? s[t - d] : 0;
        __syncthreads();
        s[t] += u;
        __syncthreads();
    }
    int ex = s[t] - v;
    bbase[t] = ex;
    gcur[t]  = ex;
    if (t == NBUCK - 1) {
        bbase[NBUCK] = s[t];   // == E
        offs[N] = E;
    }
}

// ---------------------------------------------------------------------------
// Binning device body: reserve contiguous per-bucket runs, write each edge
// once as packed word src | (dst & 127) << 17 (N < 2^17).
// ---------------------------------------------------------------------------
__device__ inline void binning_body(const int* __restrict__ ei, int E, int chunk,
                                    int* __restrict__ gcur, unsigned* __restrict__ ebuf,
                                    int* lh) {
    int t = threadIdx.x;
    for (int i = t; i < NBUCK; i += 256) lh[i] = 0;
    __syncthreads();
    int base = chunk * EPB_BIN;
    int lim  = min(E, base + EPB_BIN);
    for (int e = base + t; e < lim; e += 256)
        atomicAdd(&lh[ei[E + e] >> BSH], 1);
    __syncthreads();
    for (int b = t; b < NBUCK; b += 256) {
        int c = lh[b];
        lh[b] = (c > 0) ? atomicAdd(&gcur[b], c) : 0;   // run base -> running cursor
    }
    __syncthreads();
    for (int e = base + t; e < lim; e += 256) {
        int d = ei[E + e];
        int srcv = ei[e];
        int pos = atomicAdd(&lh[d >> BSH], 1);
        ebuf[pos] = (unsigned)srcv | ((unsigned)(d & (BW - 1)) << 17);
    }
}

__launch_bounds__(256)
__global__ void binning_kernel(const int* __restrict__ ei, int E,
                               int* __restrict__ gcur, unsigned* __restrict__ ebuf) {
    __shared__ int lh[NBUCK];
    binning_body(ei, E, blockIdx.x, gcur, ebuf, lh);
}

// ---------------------------------------------------------------------------
// Fused kernel: blocks [0, NBIN) do binning (latency-bound, start first);
// blocks [NBIN, NBIN+G1T) do hs_bf16 = bf16(x @ W1): 64-row tile, 4x4 per
// thread. W1 in LDS (16 KB, conflict-free); x read directly from global
// (16-lane broadcast per row). unroll 4 doubles loads-in-flight vs r10's
// unroll 2 (the GEMM half has been pinned at ~50 us across all binning
// variants -> load-latency-bound). __launch_bounds__(256,4) caps VGPRs at 128
// (r9 lesson: full unroll -> 240 VGPRs -> 9.6% occupancy).
// ---------------------------------------------------------------------------
__launch_bounds__(256, 4)
__global__ void gemm1_binning_kernel(const float* __restrict__ x, const float* __restrict__ W1,
                                     unsigned short* __restrict__ hsb,
                                     const int* __restrict__ ei, int E,
                                     int* __restrict__ gcur, unsigned* __restrict__ ebuf,
                                     int N, int NBIN) {
    __shared__ float smem[FIN * FH];    // 16 KB: Ws for gemm, lh (4 KB) for binning
    int tid = threadIdx.x;
    if ((int)blockIdx.x < NBIN) {
        binning_body(ei, E, (int)blockIdx.x, gcur, ebuf, (int*)smem);
        return;
    }
    // ---- GEMM phase ----
    float* Ws = smem;                  // [64][64] row-major (k, col)
    {
        const float4* W14 = (const float4*)W1;
        float4* Ws4 = (float4*)smem;
        for (int i = tid; i < 1024; i += 256) Ws4[i] = W14[i];
    }
    __syncthreads();
    int cg = tid & 15;                 // col group: cols cg*4..+3
    int rg = tid >> 4;                 // row group: rows rg*4..+3
    int rowBase = ((int)blockIdx.x - NBIN) * 64;
    int r0 = rowBase + rg * 4;
    const float4* x4 = (const float4*)x;
    size_t ra = (size_t)min(r0 + 0, N - 1) * 16;
    size_t rb = (size_t)min(r0 + 1, N - 1) * 16;
    size_t rc = (size_t)min(r0 + 2, N - 1) * 16;
    size_t rd = (size_t)min(r0 + 3, N - 1) * 16;
    float4 acc0 = {0,0,0,0}, acc1 = {0,0,0,0}, acc2 = {0,0,0,0}, acc3 = {0,0,0,0};
    #pragma unroll 4
    for (int kc = 0; kc < 16; ++kc) {
        float4 xa0 = x4[ra + kc];
        float4 xa1 = x4[rb + kc];
        float4 xa2 = x4[rc + kc];
        float4 xa3 = x4[rd + kc];
        const float* xa0f = (const float*)&xa0;
        const float* xa1f = (const float*)&xa1;
        const float* xa2f = (const float*)&xa2;
        const float* xa3f = (const float*)&xa3;
        #pragma unroll
        for (int j = 0; j < 4; ++j) {
            float4 wv = *(const float4*)&Ws[(kc * 4 + j) * FH + cg * 4];
            float v0 = xa0f[j], v1 = xa1f[j], v2 = xa2f[j], v3 = xa3f[j];
            acc0.x = fmaf(v0, wv.x, acc0.x); acc0.y = fmaf(v0, wv.y, acc0.y);
            acc0.z = fmaf(v0, wv.z, acc0.z); acc0.w = fmaf(v0, wv.w, acc0.w);
            acc1.x = fmaf(v1, wv.x, acc1.x); acc1.y = fmaf(v1, wv.y, acc1.y);
            acc1.z = fmaf(v1, wv.z, acc1.z); acc1.w = fmaf(v1, wv.w, acc1.w);
            acc2.x = fmaf(v2, wv.x, acc2.x); acc2.y = fmaf(v2, wv.y, acc2.y);
            acc2.z = fmaf(v2, wv.z, acc2.z); acc2.w = fmaf(v2, wv.w, acc2.w);
            acc3.x = fmaf(v3, wv.x, acc3.x); acc3.y = fmaf(v3, wv.y, acc3.y);
            acc3.z = fmaf(v3, wv.z, acc3.z); acc3.w = fmaf(v3, wv.w, acc3.w);
        }
    }
    ushort4* hsb4 = (ushort4*)hsb;
    if (r0 + 0 < N) hsb4[(size_t)(r0 + 0) * 16 + cg] =
        make_ushort4(f2bf(acc0.x), f2bf(acc0.y), f2bf(acc0.z), f2bf(acc0.w));
    if (r0 + 1 < N) hsb4[(size_t)(r0 + 1) * 16 + cg] =
        make_ushort4(f2bf(acc1.x), f2bf(acc1.y), f2bf(acc1.z), f2bf(acc1.w));
    if (r0 + 2 < N) hsb4[(size_t)(r0 + 2) * 16 + cg] =
        make_ushort4(f2bf(acc2.x), f2bf(acc2.y), f2bf(acc2.z), f2bf(acc2.w));
    if (r0 + 3 < N) hsb4[(size_t)(r0 + 3) * 16 + cg] =
        make_ushort4(f2bf(acc3.x), f2bf(acc3.y), f2bf(acc3.z), f2bf(acc3.w));
}

// ---------------------------------------------------------------------------
// Kernel: per-bucket CSR build + dinv + offs. One block per bucket; all csr
// stores land in the block's own contiguous region (single-owner lines).
// ---------------------------------------------------------------------------
__launch_bounds__(256)
__global__ void bucket_csr_kernel(const unsigned* __restrict__ ebuf,
                                  const int* __restrict__ bbase,
                                  int* __restrict__ csr, int* __restrict__ offs,
                                  float* __restrict__ dinv, int N) {
    __shared__ int cnt[BW], sc[BW], cur[BW];
    int t = threadIdx.x;
    int b = blockIdx.x;
    if (t < BW) cnt[t] = 0;
    __syncthreads();
    int beg = bbase[b], end = bbase[b + 1];
    for (int i = beg + t; i < end; i += 256)
        atomicAdd(&cnt[ebuf[i] >> 17], 1);
    __syncthreads();
    if (t < BW) sc[t] = cnt[t];
    __syncthreads();
    for (int d = 1; d < BW; d <<= 1) {
        int u = (t < BW && t >= d) ? sc[t - d] : 0;
        __syncthreads();
        if (t < BW) sc[t] += u;
        __syncthreads();
    }
    int nodeBase = b << BSH;
    if (t < BW) {
        int node = nodeBase + t;
        int ex = beg + sc[t] - cnt[t];
        cur[t] = ex;
        if (node < N) {
            offs[node] = ex;
            dinv[node] = rsqrtf((float)(cnt[t] + 1));
        }
    }
    __syncthreads();
    for (int i = beg + t; i < end; i += 256) {
        unsigned w = ebuf[i];
        int pos = atomicAdd(&cur[w >> 17], 1);
        csr[pos] = (int)(w & 0x1FFFF);
    }
}

// ---------------------------------------------------------------------------
// Kernel: layer-1 PULL aggregation (bf16 gathers, 8 in flight, per-src dinv
// scale in-reg) fused with finalize1 + GEMM2; writes hs2 pre-scaled as bf16.
// 16 nodes/block; 16 lanes per node, lane owns one ushort4 chunk (4 feats).
// ---------------------------------------------------------------------------
__launch_bounds__(256)
__global__ void agg1_gemm2_kernel(const unsigned short* __restrict__ hsb,
                                  const int* __restrict__ csr,
                                  const int* __restrict__ offs, const float* __restrict__ dinv,
                                  const float* __restrict__ b1, const float* __restrict__ W2,
                                  unsigned short* __restrict__ hs2b, int N) {
    __shared__ float W2s[FH * FO];       // 4 KB
    __shared__ float h1s[16][68];        // 68-float row stride (16B-aligned, non-pow2)
    const ushort4* hs4 = (const ushort4*)hsb;   // 16 ushort4 per row
    int tid = threadIdx.x;
    for (int i = tid; i < FH * FO; i += 256) W2s[i] = W2[i];
    int g = tid >> 4, l = tid & 15;
    int n = blockIdx.x * 16 + g;
    if (n < N) {
        float di_n = dinv[n];
        float4 self = bf4_to_f4(hs4[(size_t)n * 16 + l]);
        float4 acc;
        acc.x = self.x * di_n; acc.y = self.y * di_n;
        acc.z = self.z * di_n; acc.w = self.w * di_n;
        int j = offs[n], end = offs[n + 1];
        for (; j + 7 < end; j += 8) {              // 8 gathers in flight
            int s0 = csr[j],     s1 = csr[j + 1], s2 = csr[j + 2], s3 = csr[j + 3];
            int s4 = csr[j + 4], s5 = csr[j + 5], s6 = csr[j + 6], s7 = csr[j + 7];
            float d0 = dinv[s0], d1 = dinv[s1], d2 = dinv[s2], d3 = dinv[s3];
            float d4 = dinv[s4], d5 = dinv[s5], d6 = dinv[s6], d7 = dinv[s7];
            float4 a0 = bf4_to_f4(hs4[(size_t)s0 * 16 + l]);
            float4 a1 = bf4_to_f4(hs4[(size_t)s1 * 16 + l]);
            float4 a2 = bf4_to_f4(hs4[(size_t)s2 * 16 + l]);
            float4 a3 = bf4_to_f4(hs4[(size_t)s3 * 16 + l]);
            float4 a4 = bf4_to_f4(hs4[(size_t)s4 * 16 + l]);
            float4 a5 = bf4_to_f4(hs4[(size_t)s5 * 16 + l]);
            float4 a6 = bf4_to_f4(hs4[(size_t)s6 * 16 + l]);
            float4 a7 = bf4_to_f4(hs4[(size_t)s7 * 16 + l]);
            acc.x += (fmaf(a0.x, d0, a1.x * d1) + fmaf(a2.x, d2, a3.x * d3))
                   + (fmaf(a4.x, d4, a5.x * d5) + fmaf(a6.x, d6, a7.x * d7));
            acc.y += (fmaf(a0.y, d0, a1.y * d1) + fmaf(a2.y, d2, a3.y * d3))
                   + (fmaf(a4.y, d4, a5.y * d5) + fmaf(a6.y, d6, a7.y * d7));
            acc.z += (fmaf(a0.z, d0, a1.z * d1) + fmaf(a2.z, d2, a3.z * d3))
                   + (fmaf(a4.z, d4, a5.z * d5) + fmaf(a6.z, d6, a7.z * d7));
            acc.w += (fmaf(a0.w, d0, a1.w * d1) + fmaf(a2.w, d2, a3.w * d3))
                   + (fmaf(a4.w, d4, a5.w * d5) + fmaf(a6.w, d6, a7.w * d7));
        }
        for (; j + 1 < end; j += 2) {
            int s0 = csr[j], s1 = csr[j + 1];
            float d0 = dinv[s0], d1 = dinv[s1];
            float4 a0 = bf4_to_f4(hs4[(size_t)s0 * 16 + l]);
            float4 a1 = bf4_to_f4(hs4[(size_t)s1 * 16 + l]);
            acc.x += fmaf(a0.x, d0, a1.x * d1);
            acc.y += fmaf(a0.y, d0, a1.y * d1);
            acc.z += fmaf(a0.z, d0, a1.z * d1);
            acc.w += fmaf(a0.w, d0, a1.w * d1);
        }
        if (j < end) {
            int s0 = csr[j];
            float d0 = dinv[s0];
            float4 a0 = bf4_to_f4(hs4[(size_t)s0 * 16 + l]);
            acc.x = fmaf(a0.x, d0, acc.x); acc.y = fmaf(a0.y, d0, acc.y);
            acc.z = fmaf(a0.z, d0, acc.z); acc.w = fmaf(a0.w, d0, acc.w);
        }
        float4 bb = ((const float4*)b1)[l];
        float4 h;
        h.x = fmaxf(fmaf(di_n, acc.x, bb.x), 0.f);
        h.y = fmaxf(fmaf(di_n, acc.y, bb.y), 0.f);
        h.z = fmaxf(fmaf(di_n, acc.z, bb.z), 0.f);
        h.w = fmaxf(fmaf(di_n, acc.w, bb.w), 0.f);
        *((float4*)&h1s[g][l * 4]) = h;
    }
    __syncthreads();
    int r = tid >> 4, o = tid & 15;     // 16 rows x 16 out-cols
    int n2 = blockIdx.x * 16 + r;
    if (n2 < N) {
        float acc = 0.f;
        #pragma unroll
        for (int jj = 0; jj < FH; ++jj)
            acc = fmaf(h1s[r][jj], W2s[jj * FO + o], acc);
        hs2b[(size_t)n2 * FO + o] = f2bf(acc * dinv[n2]);   // pre-scaled bf16
    }
}

// ---------------------------------------------------------------------------
// Kernel: layer-2 PULL aggregation (8 gathers in flight) + bias + log_softmax.
// hs2b table is 3.2 MB -> fits per-XCD L2; gathers are 2B/lane.
// ---------------------------------------------------------------------------
__launch_bounds__(256)
__global__ void agg2_softmax_kernel(const unsigned short* __restrict__ hs2b,
                                    const int* __restrict__ csr,
                                    const int* __restrict__ offs, const float* __restrict__ dinv,
                                    const float* __restrict__ b2, float* __restrict__ out, int N) {
    int tid = threadIdx.x;
    int g = tid >> 4, o = tid & 15;
    int n = blockIdx.x * 16 + g;
    float v = 0.f;
    if (n < N) {
        float acc = bf2f(hs2b[(size_t)n * 16 + o]);    // self loop (pre-scaled)
        int j = offs[n], end = offs[n + 1];
        for (; j + 7 < end; j += 8) {
            int s0 = csr[j],     s1 = csr[j + 1], s2 = csr[j + 2], s3 = csr[j + 3];
            int s4 = csr[j + 4], s5 = csr[j + 5], s6 = csr[j + 6], s7 = csr[j + 7];
            float t0 = bf2f(hs2b[(size_t)s0 * 16 + o]) + bf2f(hs2b[(size_t)s1 * 16 + o]);
            float t1 = bf2f(hs2b[(size_t)s2 * 16 + o]) + bf2f(hs2b[(size_t)s3 * 16 + o]);
            float t2 = bf2f(hs2b[(size_t)s4 * 16 + o]) + bf2f(hs2b[(size_t)s5 * 16 + o]);
            float t3 = bf2f(hs2b[(size_t)s6 * 16 + o]) + bf2f(hs2b[(size_t)s7 * 16 + o]);
            acc += (t0 + t1) + (t2 + t3);
        }
        for (; j < end; ++j) acc += bf2f(hs2b[(size_t)csr[j] * 16 + o]);
        v = fmaf(dinv[n], acc, b2[o]);
    }
    float m = v;
    #pragma unroll
    for (int s = 8; s >= 1; s >>= 1) m = fmaxf(m, __shfl_xor(m, s, 64));
    float ex = __expf(v - m);
    float sum = ex;
    #pragma unroll
    for (int s = 8; s >= 1; s >>= 1) sum += __shfl_xor(sum, s, 64);
    if (n < N) out[(size_t)n * FO + o] = v - m - __logf(sum);
}

// ---------------------------------------------------------------------------
extern "C" void kernel_launch(void* const* d_in, const int* in_sizes, int n_in,
                              void* d_out, int out_size, void* d_ws, size_t ws_size,
                              hipStream_t stream) {
    const float* x  = (const float*)d_in[0];
    const int*   ei = (const int*)d_in[1];     // int32
    const float* W1 = (const float*)d_in[2];
    const float* b1 = (const float*)d_in[3];
    const float* W2 = (const float*)d_in[4];
    const float* b2 = (const float*)d_in[5];
    float* out = (float*)d_out;

    const int N = in_sizes[0] / FIN;
    const int E = in_sizes[1] / 2;
    const int NCH  = (E + EPB_HIST - 1) / EPB_HIST;  // hist blocks
    const int NCB  = (E + EPB_BIN - 1) / EPB_BIN;    // binning blocks
    const int NB4  = (N + BW - 1) / BW;              // buckets actually used
    const int G1T  = (N + 63) / 64;                  // gemm 64-row tiles
    const int GA   = (N + 15) / 16;                  // agg blocks

    char* ws = (char*)d_ws;
    size_t off = 0;
    auto alloc = [&](size_t bytes) -> void* {
        off = (off + 255) & ~(size_t)255;
        void* p = ws + off;
        off += bytes;
        return p;
    };
    float*          dinv  = (float*)alloc((size_t)N * 4);               //  0.4 MB
    unsigned short* hsb   = (unsigned short*)alloc((size_t)N * FH * 2); // 12.8 MB
    unsigned short* hs2b  = (unsigned short*)alloc((size_t)N * FO * 2); //  3.2 MB
    int*            offs  = (int*)alloc((size_t)(N + 1) * 4);           //  0.4 MB
    int*            bcnt  = (int*)alloc(NBUCK * 4);
    int*            bbase = (int*)alloc((NBUCK + 1) * 4);
    int*            gcur  = (int*)alloc(NBUCK * 4);
    // ebuf + csr (2*E ints = 12.8 MB): in ws if it fits, else alias the x
    // input buffer (25.6 MB, dead after the gemm phase; harness restores d_in
    // before every launch; ws_size constant -> capture-stable branch).
    unsigned* ebuf;
    int*      csr;
    bool ws_fits = (ws_size >= off + 512 + (size_t)E * 8);
    if (ws_fits) {
        ebuf = (unsigned*)alloc((size_t)E * 4);
        csr  = (int*)     alloc((size_t)E * 4);
    } else {
        ebuf = (unsigned*)x;
        csr  = (int*)x + E;
    }

    hipMemsetAsync(bcnt, 0, NBUCK * 4, stream);

    hist_kernel<<<NCH, 256, 0, stream>>>(ei, E, bcnt);
    bucket_scan_kernel<<<1, NBUCK, 0, stream>>>(bcnt, bbase, gcur, offs, N, E);
    if (ws_fits) {
        // Overlap: binning blocks first (latency-bound), gemm blocks backfill.
        gemm1_binning_kernel<<<NCB + G1T, 256, 0, stream>>>(x, W1, hsb, ei, E,
                                                            gcur, ebuf, N, NCB);
    } else {
        // ebuf aliases x: gemm must fully precede binning.
        gemm1_binning_kernel<<<G1T, 256, 0, stream>>>(x, W1, hsb, ei, E,
                                                      gcur, ebuf, N, 0);
        binning_kernel<<<NCB, 256, 0, stream>>>(ei, E, gcur, ebuf);
    }
    bucket_csr_kernel<<<NB4, 256, 0, stream>>>(ebuf, bbase, csr, offs, dinv, N);
    agg1_gemm2_kernel<<<GA, 256, 0, stream>>>(hsb, csr, offs, dinv, b1, W2, hs2b, N);
    agg2_softmax_kernel<<<GA, 256, 0, stream>>>(hs2b, csr, offs, dinv, b2, out, N);
}